// Round 2
// baseline (4606.793 us; speedup 1.0000x reference)
//
#include <hip/hip_runtime.h>
#include <cstddef>

// Problem constants (MultiHeadKvtAttention): B=8, N=1024, DIM=768, H=12, D=64, TOPK=100
#define DIMC 768
#define HEADS 12
#define HEAD_DIM 64
#define TOPK 100
#define SCALE 0.125f
#define BATCH 8
#define SEQ 1024
#define RB 8       // rows per attention block (one 64-lane wave per row)
#define CAP 256    // compacted-index capacity per row (fallback loop if exceeded)
#define ATHR 512   // attn block threads = RB waves

__device__ __forceinline__ unsigned mkey(float f) {
  // monotonic float->uint transform: a > b  <=>  mkey(a) > mkey(b)
  unsigned u = __float_as_uint(f);
  return u ^ ((unsigned)((int)u >> 31) | 0x80000000u);
}

// ---------------------------------------------------------------------------
// fp32 GEMM: C[M,N] = A[M,K] @ W[K,N] (+ bias). 128x128 tile, K-step 16,
// 256 threads, 8x8 micro-tile per thread. (unchanged from round 0)
// ---------------------------------------------------------------------------
template <bool BIAS>
__global__ __launch_bounds__(256) void gemm_f32(
    const float* __restrict__ A, const float* __restrict__ W,
    const float* __restrict__ bias, float* __restrict__ C,
    int M, int K, int N) {
  __shared__ float Al[16][128];  // A tile, transposed: Al[k][m]
  __shared__ float Bl[16][128];  // W tile: Bl[k][n]
  const int t = threadIdx.x;
  const int row0 = blockIdx.y * 128, col0 = blockIdx.x * 128;
  const int tx = t & 15, ty = t >> 4;

  const int a_r = t >> 2, a_c = (t & 3) * 4;     // A: 128 rows x 16 cols
  const int b_r = t >> 5, b_c = (t & 31) * 4;    // W: 16 rows x 128 cols
  const float* Ap0 = A + (size_t)(row0 + a_r) * K + a_c;
  const float* Ap1 = A + (size_t)(row0 + a_r + 64) * K + a_c;
  const float* Wp0 = W + (size_t)b_r * N + col0 + b_c;
  const float* Wp1 = W + (size_t)(b_r + 8) * N + col0 + b_c;

  float acc[8][8];
#pragma unroll
  for (int i = 0; i < 8; ++i)
#pragma unroll
    for (int j = 0; j < 8; ++j) acc[i][j] = 0.f;

  for (int k0 = 0; k0 < K; k0 += 16) {
    float4 a0 = *(const float4*)(Ap0 + k0);
    float4 a1 = *(const float4*)(Ap1 + k0);
    float4 w0 = *(const float4*)(Wp0 + (size_t)k0 * N);
    float4 w1 = *(const float4*)(Wp1 + (size_t)k0 * N);
    Al[a_c + 0][a_r] = a0.x; Al[a_c + 1][a_r] = a0.y;
    Al[a_c + 2][a_r] = a0.z; Al[a_c + 3][a_r] = a0.w;
    Al[a_c + 0][a_r + 64] = a1.x; Al[a_c + 1][a_r + 64] = a1.y;
    Al[a_c + 2][a_r + 64] = a1.z; Al[a_c + 3][a_r + 64] = a1.w;
    *(float4*)&Bl[b_r][b_c] = w0;
    *(float4*)&Bl[b_r + 8][b_c] = w1;
    __syncthreads();
#pragma unroll
    for (int kk = 0; kk < 16; ++kk) {
      float av[8], bv[8];
      *(float4*)&av[0] = *(const float4*)&Al[kk][ty * 8];
      *(float4*)&av[4] = *(const float4*)&Al[kk][ty * 8 + 4];
      *(float4*)&bv[0] = *(const float4*)&Bl[kk][tx * 8];
      *(float4*)&bv[4] = *(const float4*)&Bl[kk][tx * 8 + 4];
#pragma unroll
      for (int i = 0; i < 8; ++i)
#pragma unroll
        for (int j = 0; j < 8; ++j) acc[i][j] = fmaf(av[i], bv[j], acc[i][j]);
    }
    __syncthreads();
  }

#pragma unroll
  for (int i = 0; i < 8; ++i) {
    float* Cp = C + (size_t)(row0 + ty * 8 + i) * N + col0 + tx * 8;
    float4 o0 = make_float4(acc[i][0], acc[i][1], acc[i][2], acc[i][3]);
    float4 o1 = make_float4(acc[i][4], acc[i][5], acc[i][6], acc[i][7]);
    if (BIAS) {
      const float* bp = bias + col0 + tx * 8;
      o0.x += bp[0]; o0.y += bp[1]; o0.z += bp[2]; o0.w += bp[3];
      o1.x += bp[4]; o1.y += bp[5]; o1.z += bp[6]; o1.w += bp[7];
    }
    *(float4*)Cp = o0;
    *(float4*)(Cp + 4) = o1;
  }
}

// ---------------------------------------------------------------------------
// Fused attention with exact top-k mask. Grid: (SEQ/RB, B*H), block 512.
// One wave per row: after the single post-score barrier, ALL phases
// (radix passes 1-3, softmax, compaction, PV) are wave-local — no block
// barriers. LDS 47.3 KB, 8 waves/block -> 3 blocks/CU = 24 waves (75% occ).
// Pass-0 radix histogram is built from registers during the score phase.
// hist[] is reused as the compacted-probability array pl[] after selection.
// ---------------------------------------------------------------------------
__global__ __launch_bounds__(ATHR, 6) void attn_topk(
    const float* __restrict__ qkv, float* __restrict__ aout) {
  __shared__ float s[RB][SEQ];              // 32 KB: raw scores (read-only after score phase)
  __shared__ unsigned hist[RB][256];        // 8 KB: radix hist; reused as pl[] after select
  __shared__ float qs[RB][HEAD_DIM];        // 2 KB: scaled q rows
  __shared__ unsigned short idxl[RB][CAP];  // 4 KB: compacted kept indices
  __shared__ unsigned selp[RB];             // selected key prefix per row
  __shared__ int selw[RB];                  // remaining rank within prefix
  __shared__ unsigned rcnt[RB];
  __shared__ float rmx[RB], rinv[RB];

  const int t = threadIdx.x;
  const int n0 = blockIdx.x * RB;
  const int bh = blockIdx.y;
  const int b = bh / HEADS, h = bh - b * HEADS;
  const float* base = qkv + (size_t)b * SEQ * (3 * DIMC) + h * HEAD_DIM;

  // ---- init: clear hist, load scaled q rows ----
  for (int i = t; i < RB * 256; i += ATHR) (&hist[0][0])[i] = 0u;
  for (int i = t; i < RB * HEAD_DIM; i += ATHR) {
    int r = i >> 6, d = i & 63;
    qs[r][d] = base[(size_t)(n0 + r) * (3 * DIMC) + d] * SCALE;
  }
  if (t < RB) { selp[t] = 0u; selw[t] = TOPK; rcnt[t] = 0u; }
  __syncthreads();

  // ---- scores: thread owns cols t and t+512, all RB rows.
  //      Builds pass-0 (top byte) histogram from registers. ----
  {
    const float* kp0 = base + DIMC + (size_t)t * (3 * DIMC);
    const float* kp1 = base + DIMC + (size_t)(t + 512) * (3 * DIMC);
    float acc0[RB], acc1[RB];
#pragma unroll
    for (int r = 0; r < RB; ++r) { acc0[r] = 0.f; acc1[r] = 0.f; }
#pragma unroll
    for (int d0 = 0; d0 < HEAD_DIM; d0 += 4) {
      float4 k0 = *(const float4*)(kp0 + d0);
      float4 k1 = *(const float4*)(kp1 + d0);
#pragma unroll
      for (int r = 0; r < RB; ++r) {
        float4 q4 = *(const float4*)&qs[r][d0];
        acc0[r] += k0.x * q4.x + k0.y * q4.y + k0.z * q4.z + k0.w * q4.w;
        acc1[r] += k1.x * q4.x + k1.y * q4.y + k1.z * q4.z + k1.w * q4.w;
      }
    }
#pragma unroll
    for (int r = 0; r < RB; ++r) {
      s[r][t] = acc0[r];
      s[r][t + 512] = acc1[r];
      atomicAdd(&hist[r][mkey(acc0[r]) >> 24], 1u);
      atomicAdd(&hist[r][mkey(acc1[r]) >> 24], 1u);
    }
  }
  __syncthreads();
  // ======== everything below is wave-local (wave w owns row w) ========

  const int row = t >> 6, l = t & 63;

  // ---- exact k-th largest: 4-pass radix select, 64 lanes/row.
  //      Pass 0's histogram is already built. ----
  for (int pass = 0; pass < 4; ++pass) {
    const int shift = 24 - pass * 8;
    if (pass > 0) {
      // clear own-row hist, then count candidates matching current prefix
#pragma unroll
      for (int j = 0; j < 4; ++j) hist[row][l * 4 + j] = 0u;
      __threadfence_block();
      const unsigned pref = selp[row];
      for (int i = l; i < SEQ; i += 64) {
        unsigned key = mkey(s[row][i]);
        if (((key ^ pref) >> (shift + 8)) == 0u)
          atomicAdd(&hist[row][(key >> shift) & 255u], 1u);
      }
      __threadfence_block();
    }
    const int want = selw[row];
    const unsigned pref2 = selp[row];
    // descending scan: lane l covers bins [255-4l .. 252-4l]
    unsigned c4[4];
    unsigned local = 0;
#pragma unroll
    for (int j = 0; j < 4; ++j) { c4[j] = hist[row][255 - 4 * l - j]; local += c4[j]; }
    unsigned incl = local;
#pragma unroll
    for (int off = 1; off < 64; off <<= 1) {
      unsigned u = __shfl_up(incl, off, 64);
      if (l >= off) incl += u;
    }
    const unsigned above = incl - local;
    if ((int)above < want && (int)incl >= want) {  // unique lane holds boundary
      unsigned run = above;
#pragma unroll
      for (int j = 0; j < 4; ++j) {
        unsigned bin = 255u - 4u * l - j;
        if (run + c4[j] >= (unsigned)want) {
          selp[row] = pref2 | (bin << shift);
          selw[row] = want - (int)run;
          break;
        }
        run += c4[j];
      }
    }
    __threadfence_block();
  }

  // ---- row max (for exp stability; also needed by overflow fallback) ----
  float mx = -1e30f;
  for (int i = l; i < SEQ; i += 64) mx = fmaxf(mx, s[row][i]);
#pragma unroll
  for (int off = 32; off > 0; off >>= 1) mx = fmaxf(mx, __shfl_xor(mx, off, 64));
  if (l == 0) rmx[row] = mx;

  // ---- softmax over kept entries + compaction (idx + prob) ----
  const unsigned thr = selp[row];  // exact key of k-th largest
  float* pl = (float*)&hist[row][0];  // reuse hist space (select is done)
  __threadfence_block();
  float sum = 0.f;
  for (int i = l; i < SEQ; i += 64) {
    float v = s[row][i];
    if (mkey(v) >= thr) {  // matches reference `attn >= kth` (ties kept)
      float p = __expf(v - mx);
      unsigned pos = atomicAdd(&rcnt[row], 1u);
      if (pos < CAP) { idxl[row][pos] = (unsigned short)i; pl[pos] = p; }
      sum += p;
    }
  }
#pragma unroll
  for (int off = 32; off > 0; off >>= 1) sum += __shfl_xor(sum, off, 64);
  if (l == 0) rinv[row] = 1.f / sum;
  __threadfence_block();

  // ---- PV: sparse gather over ~TOPK kept columns, unrolled x8 ----
  {
    const float* vb = base + 2 * DIMC;
    const unsigned cnt = rcnt[row];
    float o = 0.f;
    if (cnt <= CAP) {
      unsigned j = 0;
      for (; j + 8 <= cnt; j += 8) {
        int m[8]; float pv[8], vv[8];
#pragma unroll
        for (int q = 0; q < 8; ++q) m[q] = idxl[row][j + q];
#pragma unroll
        for (int q = 0; q < 8; ++q) pv[q] = pl[j + q];
#pragma unroll
        for (int q = 0; q < 8; ++q) vv[q] = vb[(size_t)m[q] * (3 * DIMC) + l];
#pragma unroll
        for (int q = 0; q < 8; ++q) o = fmaf(pv[q], vv[q], o);
      }
      for (; j < cnt; ++j) {
        int m = idxl[row][j];
        o = fmaf(pl[j], vb[(size_t)m * (3 * DIMC) + l], o);
      }
    } else {  // tie-overflow fallback (vanishingly rare with continuous data)
      const float mx2 = rmx[row];
      for (int m = 0; m < SEQ; ++m) {
        float v = s[row][m];
        if (mkey(v) >= thr) o = fmaf(__expf(v - mx2), vb[(size_t)m * (3 * DIMC) + l], o);
      }
    }
    aout[((size_t)b * SEQ + n0 + row) * DIMC + h * HEAD_DIM + l] = o * rinv[row];
  }
}

// ---------------------------------------------------------------------------
extern "C" void kernel_launch(void* const* d_in, const int* in_sizes, int n_in,
                              void* d_out, int out_size, void* d_ws, size_t ws_size,
                              hipStream_t stream) {
  (void)in_sizes; (void)n_in; (void)out_size; (void)ws_size;
  const float* x      = (const float*)d_in[0];  // [8,1024,768]
  const float* w_qkv  = (const float*)d_in[1];  // [768,2304]
  const float* w_proj = (const float*)d_in[2];  // [768,768]
  const float* b_proj = (const float*)d_in[3];  // [768]
  float* out = (float*)d_out;                   // [8,1024,768]

  const int M = BATCH * SEQ;                    // 8192
  float* qkv  = (float*)d_ws;                   // [8192, 2304]  (75.5 MB)
  float* aatt = qkv + (size_t)M * (3 * DIMC);   // [8192, 768]   (25.2 MB)

  // 1) QKV projection
  dim3 g1((3 * DIMC) / 128, M / 128);
  gemm_f32<false><<<g1, dim3(256), 0, stream>>>(x, w_qkv, nullptr, qkv,
                                                M, DIMC, 3 * DIMC);
  // 2) fused top-k attention
  dim3 g2(SEQ / RB, BATCH * HEADS);
  attn_topk<<<g2, dim3(ATHR), 0, stream>>>(qkv, aatt);
  // 3) output projection + bias
  dim3 g3(DIMC / 128, M / 128);
  gemm_f32<true><<<g3, dim3(256), 0, stream>>>(aatt, w_proj, b_proj, out,
                                               M, DIMC, DIMC);
}

// Round 3
// 2198.685 us; speedup vs baseline: 2.0952x; 2.0952x over previous
//
#include <hip/hip_runtime.h>
#include <cstddef>

// Problem constants (MultiHeadKvtAttention): B=8, N=1024, DIM=768, H=12, D=64, TOPK=100
#define DIMC 768
#define HEADS 12
#define HEAD_DIM 64
#define TOPK 100
#define SCALE 0.125f
#define BATCH 8
#define SEQ 1024
#define RB 4       // rows per attention block (one 64-lane wave per row)
#define CAP 256    // compacted-index capacity per row (fallback loop if exceeded)

__device__ __forceinline__ unsigned mkey(float f) {
  // monotonic float->uint transform: a > b  <=>  mkey(a) > mkey(b)
  unsigned u = __float_as_uint(f);
  return u ^ ((unsigned)((int)u >> 31) | 0x80000000u);
}

// ---------------------------------------------------------------------------
// fp32 GEMM: C[M,N] = A[M,K] @ W[K,N] (+ bias). 128x128 tile, K-step 16,
// 256 threads, 8x8 micro-tile per thread. (unchanged; ~450 us combined)
// ---------------------------------------------------------------------------
template <bool BIAS>
__global__ __launch_bounds__(256) void gemm_f32(
    const float* __restrict__ A, const float* __restrict__ W,
    const float* __restrict__ bias, float* __restrict__ C,
    int M, int K, int N) {
  __shared__ float Al[16][128];  // A tile, transposed: Al[k][m]
  __shared__ float Bl[16][128];  // W tile: Bl[k][n]
  const int t = threadIdx.x;
  const int row0 = blockIdx.y * 128, col0 = blockIdx.x * 128;
  const int tx = t & 15, ty = t >> 4;

  const int a_r = t >> 2, a_c = (t & 3) * 4;     // A: 128 rows x 16 cols
  const int b_r = t >> 5, b_c = (t & 31) * 4;    // W: 16 rows x 128 cols
  const float* Ap0 = A + (size_t)(row0 + a_r) * K + a_c;
  const float* Ap1 = A + (size_t)(row0 + a_r + 64) * K + a_c;
  const float* Wp0 = W + (size_t)b_r * N + col0 + b_c;
  const float* Wp1 = W + (size_t)(b_r + 8) * N + col0 + b_c;

  float acc[8][8];
#pragma unroll
  for (int i = 0; i < 8; ++i)
#pragma unroll
    for (int j = 0; j < 8; ++j) acc[i][j] = 0.f;

  for (int k0 = 0; k0 < K; k0 += 16) {
    float4 a0 = *(const float4*)(Ap0 + k0);
    float4 a1 = *(const float4*)(Ap1 + k0);
    float4 w0 = *(const float4*)(Wp0 + (size_t)k0 * N);
    float4 w1 = *(const float4*)(Wp1 + (size_t)k0 * N);
    Al[a_c + 0][a_r] = a0.x; Al[a_c + 1][a_r] = a0.y;
    Al[a_c + 2][a_r] = a0.z; Al[a_c + 3][a_r] = a0.w;
    Al[a_c + 0][a_r + 64] = a1.x; Al[a_c + 1][a_r + 64] = a1.y;
    Al[a_c + 2][a_r + 64] = a1.z; Al[a_c + 3][a_r + 64] = a1.w;
    *(float4*)&Bl[b_r][b_c] = w0;
    *(float4*)&Bl[b_r + 8][b_c] = w1;
    __syncthreads();
#pragma unroll
    for (int kk = 0; kk < 16; ++kk) {
      float av[8], bv[8];
      *(float4*)&av[0] = *(const float4*)&Al[kk][ty * 8];
      *(float4*)&av[4] = *(const float4*)&Al[kk][ty * 8 + 4];
      *(float4*)&bv[0] = *(const float4*)&Bl[kk][tx * 8];
      *(float4*)&bv[4] = *(const float4*)&Bl[kk][tx * 8 + 4];
#pragma unroll
      for (int i = 0; i < 8; ++i)
#pragma unroll
        for (int j = 0; j < 8; ++j) acc[i][j] = fmaf(av[i], bv[j], acc[i][j]);
    }
    __syncthreads();
  }

#pragma unroll
  for (int i = 0; i < 8; ++i) {
    float* Cp = C + (size_t)(row0 + ty * 8 + i) * N + col0 + tx * 8;
    float4 o0 = make_float4(acc[i][0], acc[i][1], acc[i][2], acc[i][3]);
    float4 o1 = make_float4(acc[i][4], acc[i][5], acc[i][6], acc[i][7]);
    if (BIAS) {
      const float* bp = bias + col0 + tx * 8;
      o0.x += bp[0]; o0.y += bp[1]; o0.z += bp[2]; o0.w += bp[3];
      o1.x += bp[4]; o1.y += bp[5]; o1.z += bp[6]; o1.w += bp[7];
    }
    *(float4*)Cp = o0;
    *(float4*)(Cp + 4) = o1;
  }
}

// ---------------------------------------------------------------------------
// Fused attention with exact top-k mask. Grid: (SEQ/RB, B*H), block 256
// (4 waves). Score phase = round-1's proven 72-VGPR structure (4 cols/thread).
// After the single post-score barrier, wave w owns row w: radix passes 1-3,
// softmax, compaction and PV are all wave-local (no block barriers).
// Pass-0 radix histogram is built from registers during the score phase.
// hist[] is reused as the compacted-probability array pl[] after selection.
// LDS = 23.6 KB -> 6 blocks/CU = 24 waves (75% occupancy).
// NOTE: do NOT add a min-waves launch_bounds hint here — round 2 showed
// (512,6) crushes the VGPR budget to 40 and spills ~7 GB to scratch.
// ---------------------------------------------------------------------------
__global__ __launch_bounds__(256) void attn_topk(
    const float* __restrict__ qkv, float* __restrict__ aout) {
  __shared__ float s[RB][SEQ];              // 16 KB: raw scores (read-only after score phase)
  __shared__ unsigned hist[RB][256];        // 4 KB: radix hist; reused as pl[] after select
  __shared__ float qs[RB][HEAD_DIM];        // 1 KB: scaled q rows
  __shared__ unsigned short idxl[RB][CAP];  // 2 KB: compacted kept indices
  __shared__ unsigned selp[RB];             // selected key prefix per row
  __shared__ int selw[RB];                  // remaining rank within prefix
  __shared__ unsigned rcnt[RB];
  __shared__ float rmx[RB], rinv[RB];

  const int t = threadIdx.x;
  const int n0 = blockIdx.x * RB;
  const int bh = blockIdx.y;
  const int b = bh / HEADS, h = bh - b * HEADS;
  const float* base = qkv + (size_t)b * SEQ * (3 * DIMC) + h * HEAD_DIM;

  // ---- init: clear hist, load scaled q rows ----
  for (int i = t; i < RB * 256; i += 256) (&hist[0][0])[i] = 0u;
  for (int i = t; i < RB * HEAD_DIM; i += 256) {
    int r = i >> 6, d = i & 63;
    qs[r][d] = base[(size_t)(n0 + r) * (3 * DIMC) + d] * SCALE;
  }
  if (t < RB) { selp[t] = 0u; selw[t] = TOPK; rcnt[t] = 0u; }
  __syncthreads();

  // ---- scores: thread owns columns m = t + mi*256 for all RB rows.
  //      Builds pass-0 (top byte) histogram from registers. ----
  {
    const float* kb = base + DIMC;
    float acc[4][RB];
#pragma unroll
    for (int mi = 0; mi < 4; ++mi)
#pragma unroll
      for (int r = 0; r < RB; ++r) acc[mi][r] = 0.f;
    for (int d0 = 0; d0 < HEAD_DIM; d0 += 4) {
      float4 k4[4];
#pragma unroll
      for (int mi = 0; mi < 4; ++mi)
        k4[mi] = *(const float4*)(kb + (size_t)(t + mi * 256) * (3 * DIMC) + d0);
#pragma unroll
      for (int r = 0; r < RB; ++r) {
        float4 q4 = *(const float4*)&qs[r][d0];
#pragma unroll
        for (int mi = 0; mi < 4; ++mi)
          acc[mi][r] += k4[mi].x * q4.x + k4[mi].y * q4.y +
                        k4[mi].z * q4.z + k4[mi].w * q4.w;
      }
    }
#pragma unroll
    for (int mi = 0; mi < 4; ++mi)
#pragma unroll
      for (int r = 0; r < RB; ++r) {
        s[r][t + mi * 256] = acc[mi][r];
        atomicAdd(&hist[r][mkey(acc[mi][r]) >> 24], 1u);
      }
  }
  __syncthreads();
  // ======== everything below is wave-local (wave w owns row w) ========

  const int row = t >> 6, l = t & 63;

  // ---- exact k-th largest: 4-pass radix select, 64 lanes/row.
  //      Pass 0's histogram is already built. ----
  for (int pass = 0; pass < 4; ++pass) {
    const int shift = 24 - pass * 8;
    if (pass > 0) {
      // clear own-row hist, then count candidates matching current prefix
#pragma unroll
      for (int j = 0; j < 4; ++j) hist[row][l * 4 + j] = 0u;
      __threadfence_block();
      const unsigned pref = selp[row];
      for (int i = l; i < SEQ; i += 64) {
        unsigned key = mkey(s[row][i]);
        if (((key ^ pref) >> (shift + 8)) == 0u)
          atomicAdd(&hist[row][(key >> shift) & 255u], 1u);
      }
      __threadfence_block();
    }
    const int want = selw[row];
    const unsigned pref2 = selp[row];
    // descending scan: lane l covers bins [255-4l .. 252-4l]
    unsigned c4[4];
    unsigned local = 0;
#pragma unroll
    for (int j = 0; j < 4; ++j) { c4[j] = hist[row][255 - 4 * l - j]; local += c4[j]; }
    unsigned incl = local;
#pragma unroll
    for (int off = 1; off < 64; off <<= 1) {
      unsigned u = __shfl_up(incl, off, 64);
      if (l >= off) incl += u;
    }
    const unsigned above = incl - local;
    if ((int)above < want && (int)incl >= want) {  // unique lane holds boundary
      unsigned run = above;
#pragma unroll
      for (int j = 0; j < 4; ++j) {
        unsigned bin = 255u - 4u * l - j;
        if (run + c4[j] >= (unsigned)want) {
          selp[row] = pref2 | (bin << shift);
          selw[row] = want - (int)run;
          break;
        }
        run += c4[j];
      }
    }
    __threadfence_block();
  }

  // ---- row max (for exp stability; also needed by overflow fallback) ----
  float mx = -1e30f;
  for (int i = l; i < SEQ; i += 64) mx = fmaxf(mx, s[row][i]);
#pragma unroll
  for (int off = 32; off > 0; off >>= 1) mx = fmaxf(mx, __shfl_xor(mx, off, 64));
  if (l == 0) rmx[row] = mx;

  // ---- softmax over kept entries + compaction (idx + prob) ----
  const unsigned thr = selp[row];  // exact key of k-th largest
  float* pl = (float*)&hist[row][0];  // reuse hist space (select is done)
  __threadfence_block();
  float sum = 0.f;
  for (int i = l; i < SEQ; i += 64) {
    float v = s[row][i];
    if (mkey(v) >= thr) {  // matches reference `attn >= kth` (ties kept)
      float p = __expf(v - mx);
      unsigned pos = atomicAdd(&rcnt[row], 1u);
      if (pos < CAP) { idxl[row][pos] = (unsigned short)i; pl[pos] = p; }
      sum += p;
    }
  }
#pragma unroll
  for (int off = 32; off > 0; off >>= 1) sum += __shfl_xor(sum, off, 64);
  if (l == 0) rinv[row] = 1.f / sum;
  __threadfence_block();

  // ---- PV: sparse gather over ~TOPK kept columns, unrolled x8 ----
  {
    const float* vb = base + 2 * DIMC;
    const unsigned cnt = rcnt[row];
    float o = 0.f;
    if (cnt <= CAP) {
      unsigned j = 0;
      for (; j + 8 <= cnt; j += 8) {
        int m[8]; float pv[8], vv[8];
#pragma unroll
        for (int q = 0; q < 8; ++q) m[q] = idxl[row][j + q];
#pragma unroll
        for (int q = 0; q < 8; ++q) pv[q] = pl[j + q];
#pragma unroll
        for (int q = 0; q < 8; ++q) vv[q] = vb[(size_t)m[q] * (3 * DIMC) + l];
#pragma unroll
        for (int q = 0; q < 8; ++q) o = fmaf(pv[q], vv[q], o);
      }
      for (; j < cnt; ++j) {
        int m = idxl[row][j];
        o = fmaf(pl[j], vb[(size_t)m * (3 * DIMC) + l], o);
      }
    } else {  // tie-overflow fallback (vanishingly rare with continuous data)
      const float mx2 = rmx[row];
      for (int m = 0; m < SEQ; ++m) {
        float v = s[row][m];
        if (mkey(v) >= thr) o = fmaf(__expf(v - mx2), vb[(size_t)m * (3 * DIMC) + l], o);
      }
    }
    aout[((size_t)b * SEQ + n0 + row) * DIMC + h * HEAD_DIM + l] = o * rinv[row];
  }
}

// ---------------------------------------------------------------------------
extern "C" void kernel_launch(void* const* d_in, const int* in_sizes, int n_in,
                              void* d_out, int out_size, void* d_ws, size_t ws_size,
                              hipStream_t stream) {
  (void)in_sizes; (void)n_in; (void)out_size; (void)ws_size;
  const float* x      = (const float*)d_in[0];  // [8,1024,768]
  const float* w_qkv  = (const float*)d_in[1];  // [768,2304]
  const float* w_proj = (const float*)d_in[2];  // [768,768]
  const float* b_proj = (const float*)d_in[3];  // [768]
  float* out = (float*)d_out;                   // [8,1024,768]

  const int M = BATCH * SEQ;                    // 8192
  float* qkv  = (float*)d_ws;                   // [8192, 2304]  (75.5 MB)
  float* aatt = qkv + (size_t)M * (3 * DIMC);   // [8192, 768]   (25.2 MB)

  // 1) QKV projection
  dim3 g1((3 * DIMC) / 128, M / 128);
  gemm_f32<false><<<g1, dim3(256), 0, stream>>>(x, w_qkv, nullptr, qkv,
                                                M, DIMC, 3 * DIMC);
  // 2) fused top-k attention
  dim3 g2(SEQ / RB, BATCH * HEADS);
  attn_topk<<<g2, dim3(256), 0, stream>>>(qkv, aatt);
  // 3) output projection + bias
  dim3 g3(DIMC / 128, M / 128);
  gemm_f32<true><<<g3, dim3(256), 0, stream>>>(aatt, w_proj, b_proj, out,
                                               M, DIMC, DIMC);
}

// Round 4
// 1179.043 us; speedup vs baseline: 3.9072x; 1.8648x over previous
//
#include <hip/hip_runtime.h>
#include <cstddef>

// Problem constants (MultiHeadKvtAttention): B=8, N=1024, DIM=768, H=12, D=64, TOPK=100
#define DIMC 768
#define HEADS 12
#define HEAD_DIM 64
#define TOPK 100
#define SCALE 0.125f
#define BATCH 8
#define SEQ 1024
#define RB 8       // rows per attention block (one 64-lane wave per row)
#define CAP 128    // compacted-index capacity per row (fallback loop if exceeded)
#define ATHR 512   // 8 waves

__device__ __forceinline__ unsigned mkey(float f) {
  // monotonic float->uint transform: a > b  <=>  mkey(a) > mkey(b)
  unsigned u = __float_as_uint(f);
  return u ^ ((unsigned)((int)u >> 31) | 0x80000000u);
}

// ---------------------------------------------------------------------------
// fp32 GEMM: C[M,N] = A[M,K] @ W[K,N] (+ bias). 128x128 tile, K-step 16,
// 256 threads, 8x8 micro-tile per thread. (unchanged; ~430 us combined)
// ---------------------------------------------------------------------------
template <bool BIAS>
__global__ __launch_bounds__(256) void gemm_f32(
    const float* __restrict__ A, const float* __restrict__ W,
    const float* __restrict__ bias, float* __restrict__ C,
    int M, int K, int N) {
  __shared__ float Al[16][128];  // A tile, transposed: Al[k][m]
  __shared__ float Bl[16][128];  // W tile: Bl[k][n]
  const int t = threadIdx.x;
  const int row0 = blockIdx.y * 128, col0 = blockIdx.x * 128;
  const int tx = t & 15, ty = t >> 4;

  const int a_r = t >> 2, a_c = (t & 3) * 4;     // A: 128 rows x 16 cols
  const int b_r = t >> 5, b_c = (t & 31) * 4;    // W: 16 rows x 128 cols
  const float* Ap0 = A + (size_t)(row0 + a_r) * K + a_c;
  const float* Ap1 = A + (size_t)(row0 + a_r + 64) * K + a_c;
  const float* Wp0 = W + (size_t)b_r * N + col0 + b_c;
  const float* Wp1 = W + (size_t)(b_r + 8) * N + col0 + b_c;

  float acc[8][8];
#pragma unroll
  for (int i = 0; i < 8; ++i)
#pragma unroll
    for (int j = 0; j < 8; ++j) acc[i][j] = 0.f;

  for (int k0 = 0; k0 < K; k0 += 16) {
    float4 a0 = *(const float4*)(Ap0 + k0);
    float4 a1 = *(const float4*)(Ap1 + k0);
    float4 w0 = *(const float4*)(Wp0 + (size_t)k0 * N);
    float4 w1 = *(const float4*)(Wp1 + (size_t)k0 * N);
    Al[a_c + 0][a_r] = a0.x; Al[a_c + 1][a_r] = a0.y;
    Al[a_c + 2][a_r] = a0.z; Al[a_c + 3][a_r] = a0.w;
    Al[a_c + 0][a_r + 64] = a1.x; Al[a_c + 1][a_r + 64] = a1.y;
    Al[a_c + 2][a_r + 64] = a1.z; Al[a_c + 3][a_r + 64] = a1.w;
    *(float4*)&Bl[b_r][b_c] = w0;
    *(float4*)&Bl[b_r + 8][b_c] = w1;
    __syncthreads();
#pragma unroll
    for (int kk = 0; kk < 16; ++kk) {
      float av[8], bv[8];
      *(float4*)&av[0] = *(const float4*)&Al[kk][ty * 8];
      *(float4*)&av[4] = *(const float4*)&Al[kk][ty * 8 + 4];
      *(float4*)&bv[0] = *(const float4*)&Bl[kk][tx * 8];
      *(float4*)&bv[4] = *(const float4*)&Bl[kk][tx * 8 + 4];
#pragma unroll
      for (int i = 0; i < 8; ++i)
#pragma unroll
        for (int j = 0; j < 8; ++j) acc[i][j] = fmaf(av[i], bv[j], acc[i][j]);
    }
    __syncthreads();
  }

#pragma unroll
  for (int i = 0; i < 8; ++i) {
    float* Cp = C + (size_t)(row0 + ty * 8 + i) * N + col0 + tx * 8;
    float4 o0 = make_float4(acc[i][0], acc[i][1], acc[i][2], acc[i][3]);
    float4 o1 = make_float4(acc[i][4], acc[i][5], acc[i][6], acc[i][7]);
    if (BIAS) {
      const float* bp = bias + col0 + tx * 8;
      o0.x += bp[0]; o0.y += bp[1]; o0.z += bp[2]; o0.w += bp[3];
      o1.x += bp[4]; o1.y += bp[5]; o1.z += bp[6]; o1.w += bp[7];
    }
    *(float4*)Cp = o0;
    *(float4*)(Cp + 4) = o1;
  }
}

// ---------------------------------------------------------------------------
// Fused attention with exact top-k mask — ATOMIC-FREE selection.
// Grid: (SEQ/RB, B*H), block 512 (8 waves). Score phase: thread owns cols
// {t, t+512} for all 8 rows, writes scores to LDS. After ONE barrier, wave w
// owns row w: loads the row's 1024 scores into 16 regs/lane, finds the exact
// k-th largest via 32-step bisection on the monotonic key (register compares
// + shfl reduce; wave-uniform, no atomics/LDS/barriers), then softmax from
// registers and ballot-based compaction. PV gathers ~TOPK V rows.
// LDS = 40 KB -> 4 blocks/CU = 32 waves (100% occupancy).
// NOTE: plain __launch_bounds__(512) — a min-waves hint (round 2) crushed
// the VGPR budget and spilled 7 GB to scratch. Never again.
// ---------------------------------------------------------------------------
__global__ __launch_bounds__(ATHR) void attn_topk(
    const float* __restrict__ qkv, float* __restrict__ aout) {
  __shared__ float s[RB][SEQ];              // 32 KB: raw scores
  __shared__ float qs[RB][HEAD_DIM];        // 2 KB: scaled q rows
  __shared__ unsigned short idxl[RB][CAP];  // 2 KB: compacted kept indices
  __shared__ float pl[RB][CAP];             // 4 KB: compacted probabilities

  const int t = threadIdx.x;
  const int n0 = blockIdx.x * RB;
  const int bh = blockIdx.y;
  const int b = bh / HEADS, h = bh - b * HEADS;
  const float* base = qkv + (size_t)b * SEQ * (3 * DIMC) + h * HEAD_DIM;

  // ---- load scaled q rows (512 threads, 512 elements: one each) ----
  {
    const int r = t >> 6, d = t & 63;
    qs[r][d] = base[(size_t)(n0 + r) * (3 * DIMC) + d] * SCALE;
  }
  __syncthreads();

  // ---- scores: thread owns columns t and t+512 for all RB rows ----
  {
    const float* kp0 = base + DIMC + (size_t)t * (3 * DIMC);
    const float* kp1 = base + DIMC + (size_t)(t + 512) * (3 * DIMC);
    float a0[RB], a1[RB];
#pragma unroll
    for (int r = 0; r < RB; ++r) { a0[r] = 0.f; a1[r] = 0.f; }
#pragma unroll
    for (int d0 = 0; d0 < HEAD_DIM; d0 += 4) {
      float4 k0 = *(const float4*)(kp0 + d0);
      float4 k1 = *(const float4*)(kp1 + d0);
#pragma unroll
      for (int r = 0; r < RB; ++r) {
        float4 q4 = *(const float4*)&qs[r][d0];
        a0[r] += k0.x * q4.x + k0.y * q4.y + k0.z * q4.z + k0.w * q4.w;
        a1[r] += k1.x * q4.x + k1.y * q4.y + k1.z * q4.z + k1.w * q4.w;
      }
    }
#pragma unroll
    for (int r = 0; r < RB; ++r) {
      s[r][t] = a0[r];
      s[r][t + 512] = a1[r];
    }
  }
  __syncthreads();
  // ======== everything below is wave-local (wave w owns row w) ========

  const int row = t >> 6, l = t & 63;

  // ---- pull row scores into registers: lane l owns cols l + 64j ----
  float sc[16];
  unsigned ky[16];
#pragma unroll
  for (int j = 0; j < 16; ++j) sc[j] = s[row][l + 64 * j];
#pragma unroll
  for (int j = 0; j < 16; ++j) ky[j] = mkey(sc[j]);

  // ---- exact k-th largest key via 32-step bisection (no atomics) ----
  // invariant: count(ky >= cur) >= TOPK; result: cur == k-th largest key
  unsigned cur = 0u;
  for (int bit = 31; bit >= 0; --bit) {
    const unsigned T = cur | (1u << bit);
    int c = 0;
#pragma unroll
    for (int j = 0; j < 16; ++j) c += (ky[j] >= T) ? 1 : 0;
#pragma unroll
    for (int off = 32; off > 0; off >>= 1) c += __shfl_xor(c, off, 64);
    if (c >= TOPK) cur = T;  // c uniform after butterfly -> no divergence
  }

  // ---- row max + masked exp + sum (all from registers) ----
  float mx = sc[0];
#pragma unroll
  for (int j = 1; j < 16; ++j) mx = fmaxf(mx, sc[j]);
#pragma unroll
  for (int off = 32; off > 0; off >>= 1) mx = fmaxf(mx, __shfl_xor(mx, off, 64));

  float p[16];
  float sum = 0.f;
#pragma unroll
  for (int j = 0; j < 16; ++j) {
    const bool keep = ky[j] >= cur;  // matches reference `attn >= kth` (ties kept)
    const float e = __expf(sc[j] - mx);
    p[j] = keep ? e : 0.f;
    sum += p[j];
  }
#pragma unroll
  for (int off = 32; off > 0; off >>= 1) sum += __shfl_xor(sum, off, 64);
  const float rinv = 1.f / sum;  // uniform

  // ---- ballot-based compaction (no atomics) ----
  unsigned cbase = 0;
#pragma unroll
  for (int j = 0; j < 16; ++j) {
    const bool keep = ky[j] >= cur;
    const unsigned long long mask = __ballot(keep);
    if (keep) {
      const unsigned pos = cbase + (unsigned)__popcll(mask & ((1ull << l) - 1ull));
      if (pos < CAP) {
        idxl[row][pos] = (unsigned short)(l + 64 * j);
        pl[row][pos] = p[j];
      }
    }
    cbase += (unsigned)__popcll(mask);
  }
  const unsigned cnt = cbase;  // uniform

  // ---- PV: sparse gather over ~TOPK kept columns, unrolled x8 ----
  {
    const float* vb = base + 2 * DIMC;
    float o = 0.f;
    if (cnt <= CAP) {
      unsigned j = 0;
      for (; j + 8 <= cnt; j += 8) {
        int m[8]; float pv[8], vv[8];
#pragma unroll
        for (int q = 0; q < 8; ++q) m[q] = idxl[row][j + q];
#pragma unroll
        for (int q = 0; q < 8; ++q) pv[q] = pl[row][j + q];
#pragma unroll
        for (int q = 0; q < 8; ++q) vv[q] = vb[(size_t)m[q] * (3 * DIMC) + l];
#pragma unroll
        for (int q = 0; q < 8; ++q) o = fmaf(pv[q], vv[q], o);
      }
      for (; j < cnt; ++j) {
        int m = idxl[row][j];
        o = fmaf(pl[row][j], vb[(size_t)m * (3 * DIMC) + l], o);
      }
    } else {  // tie-overflow fallback (needs cnt > CAP: vanishingly rare)
      for (int m = 0; m < SEQ; ++m) {
        float v = s[row][m];
        if (mkey(v) >= cur) o = fmaf(__expf(v - mx), vb[(size_t)m * (3 * DIMC) + l], o);
      }
    }
    aout[((size_t)b * SEQ + n0 + row) * DIMC + h * HEAD_DIM + l] = o * rinv;
  }
}

// ---------------------------------------------------------------------------
extern "C" void kernel_launch(void* const* d_in, const int* in_sizes, int n_in,
                              void* d_out, int out_size, void* d_ws, size_t ws_size,
                              hipStream_t stream) {
  (void)in_sizes; (void)n_in; (void)out_size; (void)ws_size;
  const float* x      = (const float*)d_in[0];  // [8,1024,768]
  const float* w_qkv  = (const float*)d_in[1];  // [768,2304]
  const float* w_proj = (const float*)d_in[2];  // [768,768]
  const float* b_proj = (const float*)d_in[3];  // [768]
  float* out = (float*)d_out;                   // [8,1024,768]

  const int M = BATCH * SEQ;                    // 8192
  float* qkv  = (float*)d_ws;                   // [8192, 2304]  (75.5 MB)
  float* aatt = qkv + (size_t)M * (3 * DIMC);   // [8192, 768]   (25.2 MB)

  // 1) QKV projection
  dim3 g1((3 * DIMC) / 128, M / 128);
  gemm_f32<false><<<g1, dim3(256), 0, stream>>>(x, w_qkv, nullptr, qkv,
                                                M, DIMC, 3 * DIMC);
  // 2) fused top-k attention
  dim3 g2(SEQ / RB, BATCH * HEADS);
  attn_topk<<<g2, dim3(ATHR), 0, stream>>>(qkv, aatt);
  // 3) output projection + bias
  dim3 g3(DIMC / 128, M / 128);
  gemm_f32<true><<<g3, dim3(256), 0, stream>>>(aatt, w_proj, b_proj, out,
                                               M, DIMC, DIMC);
}

// Round 5
// 743.133 us; speedup vs baseline: 6.1991x; 1.5866x over previous
//
#include <hip/hip_runtime.h>
#include <cstddef>

// Problem constants (MultiHeadKvtAttention): B=8, N=1024, DIM=768, H=12, D=64, TOPK=100
#define DIMC 768
#define HEADS 12
#define HEAD_DIM 64
#define TOPK 100
#define SCALE 0.125f
#define BATCH 8
#define SEQ 1024
#define RB 8       // rows per attention block (one 64-lane wave per row)
#define CAP 128    // compacted-index capacity per row (fallback loop if exceeded)
#define ATHR 512   // 8 waves

typedef __attribute__((ext_vector_type(8))) __bf16 bf16x8;
typedef __attribute__((ext_vector_type(4))) float f32x4;
typedef unsigned short u16;

__device__ __forceinline__ unsigned mkey(float f) {
  // monotonic float->uint transform: a > b  <=>  mkey(a) > mkey(b)
  unsigned u = __float_as_uint(f);
  return u ^ ((unsigned)((int)u >> 31) | 0x80000000u);
}

// Exact 2-way split: f == hi + lo + O(2^-16 |f|); hi,lo are bf16 bit patterns.
// hi = truncated top 16 bits; lo = bf16_trunc(f - hi). Dropped Al@Bl term in
// the 3-product GEMM is O(2^-16) relative — far below fp32 noise floor.
__device__ __forceinline__ void split_pack4(float4 f, uint2& ph, uint2& pl) {
  unsigned u0 = __float_as_uint(f.x), u1 = __float_as_uint(f.y);
  unsigned u2 = __float_as_uint(f.z), u3 = __float_as_uint(f.w);
  float r0 = f.x - __uint_as_float(u0 & 0xFFFF0000u);
  float r1 = f.y - __uint_as_float(u1 & 0xFFFF0000u);
  float r2 = f.z - __uint_as_float(u2 & 0xFFFF0000u);
  float r3 = f.w - __uint_as_float(u3 & 0xFFFF0000u);
  ph.x = (u0 >> 16) | (u1 & 0xFFFF0000u);
  ph.y = (u2 >> 16) | (u3 & 0xFFFF0000u);
  pl.x = (__float_as_uint(r0) >> 16) | (__float_as_uint(r1) & 0xFFFF0000u);
  pl.y = (__float_as_uint(r2) >> 16) | (__float_as_uint(r3) & 0xFFFF0000u);
}

// ---------------------------------------------------------------------------
// Split-bf16 MFMA GEMM: C[M,N] = A[M,K] @ W[K,N] (+bias), fp32-accurate via
// Ah@Wh + Ah@Wl + Al@Wh (3x mfma_f32_16x16x32_bf16).
// Block 256 (4 waves, 2x2 wave grid, 64x64 out each), tile 128x128, BK=32.
// A_SPLIT=0: A is fp32, split during staging. A_SPLIT=1: A pre-split (Ah_g/Al_g).
// W always fp32 [K,N]; staged transposed [n][k] via along-K loads (coalesced
// across 128 consecutive cols per k-row).
// MFMA fragment maps (m89/m91 HW-verified): A row=lane&15,k=(lane>>4)*8+reg;
// B col=lane&15,k=(lane>>4)*8+reg (hence [n][k] LDS); C/D col=lane&15,
// row=(lane>>4)*4+reg.
// ---------------------------------------------------------------------------
template <int A_SPLIT, bool BIAS>
__global__ __launch_bounds__(256) void gemm_mfma_split(
    const float* __restrict__ Af,
    const u16* __restrict__ Ah_g, const u16* __restrict__ Al_g,
    const float* __restrict__ W,
    const float* __restrict__ bias, float* __restrict__ C,
    int M, int K, int N) {
  __shared__ u16 Ah[128][32], Al[128][32];  // [m][k]
  __shared__ u16 Bh[128][32], Bl[128][32];  // [n][k] (transposed W)

  const int t = threadIdx.x;
  const int w = t >> 6, l = t & 63;
  const int wr = w >> 1, wc = w & 1;
  const int row0 = blockIdx.y * 128, col0 = blockIdx.x * 128;
  const int fr = l & 15, fq = l >> 4;  // fragment row/col and k-group

  f32x4 acc[4][4];
#pragma unroll
  for (int i = 0; i < 4; ++i)
#pragma unroll
    for (int j = 0; j < 4; ++j) acc[i][j] = (f32x4){0.f, 0.f, 0.f, 0.f};

  // staging maps
  const int a_row = t >> 1;                 // A: 2 threads/row
  const int a_k0 = (t & 1) * 16;            // each covers 16 k
  const int w_col = t & 127;                // W: thread owns one col
  const int w_kh = (t >> 7) * 16;           // and 16 k values

  for (int k0 = 0; k0 < K; k0 += 32) {
    // ---- stage A ----
    if constexpr (A_SPLIT == 0) {
      const float* ap = Af + (size_t)(row0 + a_row) * K + k0 + a_k0;
#pragma unroll
      for (int q = 0; q < 4; ++q) {
        float4 v = *(const float4*)(ap + q * 4);
        uint2 ph, pl;
        split_pack4(v, ph, pl);
        *(uint2*)&Ah[a_row][a_k0 + q * 4] = ph;
        *(uint2*)&Al[a_row][a_k0 + q * 4] = pl;
      }
    } else {
      const size_t off = (size_t)(row0 + a_row) * K + k0 + a_k0;
      *(uint4*)&Ah[a_row][a_k0] = *(const uint4*)(Ah_g + off);
      *(uint4*)&Ah[a_row][a_k0 + 8] = *(const uint4*)(Ah_g + off + 8);
      *(uint4*)&Al[a_row][a_k0] = *(const uint4*)(Al_g + off);
      *(uint4*)&Al[a_row][a_k0 + 8] = *(const uint4*)(Al_g + off + 8);
    }
    // ---- stage W (transpose + split) ----
    {
      const float* wp = W + (size_t)(k0 + w_kh) * N + col0 + w_col;
      float wv[16];
#pragma unroll
      for (int j = 0; j < 16; ++j) wv[j] = wp[(size_t)j * N];
#pragma unroll
      for (int g = 0; g < 4; ++g) {
        float4 v = make_float4(wv[g * 4], wv[g * 4 + 1], wv[g * 4 + 2], wv[g * 4 + 3]);
        uint2 ph, pl;
        split_pack4(v, ph, pl);
        *(uint2*)&Bh[w_col][w_kh + g * 4] = ph;
        *(uint2*)&Bl[w_col][w_kh + g * 4] = pl;
      }
    }
    __syncthreads();

    // ---- fragments + 48 MFMA ----
    bf16x8 fah[4], fal[4], fbh[4], fbl[4];
#pragma unroll
    for (int mf = 0; mf < 4; ++mf) {
      fah[mf] = *(const bf16x8*)&Ah[wr * 64 + mf * 16 + fr][fq * 8];
      fal[mf] = *(const bf16x8*)&Al[wr * 64 + mf * 16 + fr][fq * 8];
    }
#pragma unroll
    for (int nf = 0; nf < 4; ++nf) {
      fbh[nf] = *(const bf16x8*)&Bh[wc * 64 + nf * 16 + fr][fq * 8];
      fbl[nf] = *(const bf16x8*)&Bl[wc * 64 + nf * 16 + fr][fq * 8];
    }
#pragma unroll
    for (int mf = 0; mf < 4; ++mf)
#pragma unroll
      for (int nf = 0; nf < 4; ++nf) {
        acc[mf][nf] = __builtin_amdgcn_mfma_f32_16x16x32_bf16(fah[mf], fbh[nf], acc[mf][nf], 0, 0, 0);
        acc[mf][nf] = __builtin_amdgcn_mfma_f32_16x16x32_bf16(fah[mf], fbl[nf], acc[mf][nf], 0, 0, 0);
        acc[mf][nf] = __builtin_amdgcn_mfma_f32_16x16x32_bf16(fal[mf], fbh[nf], acc[mf][nf], 0, 0, 0);
      }
    __syncthreads();
  }

  // ---- epilogue: C/D map col=lane&15, row=(lane>>4)*4+reg ----
#pragma unroll
  for (int mf = 0; mf < 4; ++mf) {
    const int r0 = row0 + wr * 64 + mf * 16 + fq * 4;
#pragma unroll
    for (int nf = 0; nf < 4; ++nf) {
      const int c = col0 + wc * 64 + nf * 16 + fr;
      float bb = 0.f;
      if (BIAS) bb = bias[c];
#pragma unroll
      for (int r = 0; r < 4; ++r)
        C[(size_t)(r0 + r) * N + c] = acc[mf][nf][r] + bb;
    }
  }
}

// ---------------------------------------------------------------------------
// Fused attention with exact top-k mask — ATOMIC-FREE selection.
// (round-4 structure; + early-exit bisection, 32-bit PV offsets, and bf16
// hi/lo split OUTPUT so the proj GEMM can consume it with MFMA directly.)
// ---------------------------------------------------------------------------
__global__ __launch_bounds__(ATHR) void attn_topk(
    const float* __restrict__ qkv,
    u16* __restrict__ aout_h, u16* __restrict__ aout_l) {
  __shared__ float s[RB][SEQ];              // 32 KB: raw scores
  __shared__ float qs[RB][HEAD_DIM];        // 2 KB: scaled q rows
  __shared__ unsigned short idxl[RB][CAP];  // 2 KB: compacted kept indices
  __shared__ float pl[RB][CAP];             // 4 KB: compacted probabilities

  const int t = threadIdx.x;
  const int n0 = blockIdx.x * RB;
  const int bh = blockIdx.y;
  const int b = bh / HEADS, h = bh - b * HEADS;
  const float* base = qkv + (size_t)b * SEQ * (3 * DIMC) + h * HEAD_DIM;

  // ---- load scaled q rows (512 threads, 512 elements: one each) ----
  {
    const int r = t >> 6, d = t & 63;
    qs[r][d] = base[(size_t)(n0 + r) * (3 * DIMC) + d] * SCALE;
  }
  __syncthreads();

  // ---- scores: thread owns columns t and t+512 for all RB rows ----
  {
    const float* kp0 = base + DIMC + (size_t)t * (3 * DIMC);
    const float* kp1 = base + DIMC + (size_t)(t + 512) * (3 * DIMC);
    float a0[RB], a1[RB];
#pragma unroll
    for (int r = 0; r < RB; ++r) { a0[r] = 0.f; a1[r] = 0.f; }
#pragma unroll
    for (int d0 = 0; d0 < HEAD_DIM; d0 += 4) {
      float4 k0 = *(const float4*)(kp0 + d0);
      float4 k1 = *(const float4*)(kp1 + d0);
#pragma unroll
      for (int r = 0; r < RB; ++r) {
        float4 q4 = *(const float4*)&qs[r][d0];
        a0[r] += k0.x * q4.x + k0.y * q4.y + k0.z * q4.z + k0.w * q4.w;
        a1[r] += k1.x * q4.x + k1.y * q4.y + k1.z * q4.z + k1.w * q4.w;
      }
    }
#pragma unroll
    for (int r = 0; r < RB; ++r) {
      s[r][t] = a0[r];
      s[r][t + 512] = a1[r];
    }
  }
  __syncthreads();
  // ======== everything below is wave-local (wave w owns row w) ========

  const int row = t >> 6, l = t & 63;

  // ---- pull row scores into registers: lane l owns cols l + 64j ----
  float sc[16];
  unsigned ky[16];
#pragma unroll
  for (int j = 0; j < 16; ++j) sc[j] = s[row][l + 64 * j];
#pragma unroll
  for (int j = 0; j < 16; ++j) ky[j] = mkey(sc[j]);

  // ---- exact k-th largest key via bisection with early exit ----
  // invariant: count(ky >= cur) >= TOPK. Early exit when count == TOPK:
  // the kept set {ky >= T} is then exactly the top-K (reference-identical,
  // including tie semantics: straddling ties make count jump past K so the
  // exit never fires and we converge to the exact k-th key).
  unsigned cur = 0u;
  for (int bit = 31; bit >= 0; --bit) {
    const unsigned T = cur | (1u << bit);
    int c = 0;
#pragma unroll
    for (int j = 0; j < 16; ++j) c += (ky[j] >= T) ? 1 : 0;
#pragma unroll
    for (int off = 32; off > 0; off >>= 1) c += __shfl_xor(c, off, 64);
    if (c >= TOPK) {  // c uniform after butterfly -> no divergence
      cur = T;
      if (c == TOPK) break;
    }
  }

  // ---- row max + masked exp + sum (all from registers) ----
  float mx = sc[0];
#pragma unroll
  for (int j = 1; j < 16; ++j) mx = fmaxf(mx, sc[j]);
#pragma unroll
  for (int off = 32; off > 0; off >>= 1) mx = fmaxf(mx, __shfl_xor(mx, off, 64));

  float p[16];
  float sum = 0.f;
#pragma unroll
  for (int j = 0; j < 16; ++j) {
    const bool keep = ky[j] >= cur;  // matches reference `attn >= kth` (ties kept)
    const float e = __expf(sc[j] - mx);
    p[j] = keep ? e : 0.f;
    sum += p[j];
  }
#pragma unroll
  for (int off = 32; off > 0; off >>= 1) sum += __shfl_xor(sum, off, 64);
  const float rinv = 1.f / sum;  // uniform

  // ---- ballot-based compaction (no atomics) ----
  unsigned cbase = 0;
#pragma unroll
  for (int j = 0; j < 16; ++j) {
    const bool keep = ky[j] >= cur;
    const unsigned long long mask = __ballot(keep);
    if (keep) {
      const unsigned pos = cbase + (unsigned)__popcll(mask & ((1ull << l) - 1ull));
      if (pos < CAP) {
        idxl[row][pos] = (unsigned short)(l + 64 * j);
        pl[row][pos] = p[j];
      }
    }
    cbase += (unsigned)__popcll(mask);
  }
  const unsigned cnt = cbase;  // uniform

  // ---- PV: sparse gather over ~TOPK kept columns, unrolled x8 ----
  {
    const float* vb = base + 2 * DIMC;
    float o = 0.f;
    if (cnt <= CAP) {
      unsigned j = 0;
      for (; j + 8 <= cnt; j += 8) {
        unsigned m[8]; float pv[8], vv[8];
#pragma unroll
        for (int q = 0; q < 8; ++q) m[q] = idxl[row][j + q];
#pragma unroll
        for (int q = 0; q < 8; ++q) pv[q] = pl[row][j + q];
#pragma unroll
        for (int q = 0; q < 8; ++q) vv[q] = vb[m[q] * (3u * DIMC) + l];
#pragma unroll
        for (int q = 0; q < 8; ++q) o = fmaf(pv[q], vv[q], o);
      }
      for (; j < cnt; ++j) {
        unsigned m = idxl[row][j];
        o = fmaf(pl[row][j], vb[m * (3u * DIMC) + l], o);
      }
    } else {  // tie-overflow fallback (needs cnt > CAP: vanishingly rare)
      for (int m = 0; m < SEQ; ++m) {
        float v = s[row][m];
        if (mkey(v) >= cur) o = fmaf(__expf(v - mx), vb[m * (3u * DIMC) + l], o);
      }
    }
    // write output as exact hi/lo bf16 split (consumed by MFMA proj GEMM)
    const float r = o * rinv;
    const unsigned u = __float_as_uint(r);
    const float rl = r - __uint_as_float(u & 0xFFFF0000u);
    const size_t idx = ((size_t)b * SEQ + n0 + row) * DIMC + h * HEAD_DIM + l;
    aout_h[idx] = (u16)(u >> 16);
    aout_l[idx] = (u16)(__float_as_uint(rl) >> 16);
  }
}

// ---------------------------------------------------------------------------
extern "C" void kernel_launch(void* const* d_in, const int* in_sizes, int n_in,
                              void* d_out, int out_size, void* d_ws, size_t ws_size,
                              hipStream_t stream) {
  (void)in_sizes; (void)n_in; (void)out_size; (void)ws_size;
  const float* x      = (const float*)d_in[0];  // [8,1024,768]
  const float* w_qkv  = (const float*)d_in[1];  // [768,2304]
  const float* w_proj = (const float*)d_in[2];  // [768,768]
  const float* b_proj = (const float*)d_in[3];  // [768]
  float* out = (float*)d_out;                   // [8,1024,768]

  const int M = BATCH * SEQ;                    // 8192
  float* qkv = (float*)d_ws;                    // [8192, 2304] fp32 (75.5 MB)
  u16* ah2 = (u16*)(qkv + (size_t)M * (3 * DIMC));  // [8192,768] bf16-hi (12.6 MB)
  u16* al2 = ah2 + (size_t)M * DIMC;                // [8192,768] bf16-lo (12.6 MB)
  // total ws = 100.66 MB (identical footprint to the proven round-0 layout)

  // 1) QKV projection (split-bf16 MFMA, fp32-accurate)
  dim3 g1((3 * DIMC) / 128, M / 128);
  gemm_mfma_split<0, false><<<g1, dim3(256), 0, stream>>>(
      x, nullptr, nullptr, w_qkv, nullptr, qkv, M, DIMC, 3 * DIMC);
  // 2) fused top-k attention (outputs hi/lo bf16 split)
  dim3 g2(SEQ / RB, BATCH * HEADS);
  attn_topk<<<g2, dim3(ATHR), 0, stream>>>(qkv, ah2, al2);
  // 3) output projection + bias (A pre-split by attn)
  dim3 g3(DIMC / 128, M / 128);
  gemm_mfma_split<1, true><<<g3, dim3(256), 0, stream>>>(
      nullptr, ah2, al2, w_proj, b_proj, out, M, DIMC, DIMC);
}

// Round 8
// 692.222 us; speedup vs baseline: 6.6551x; 1.0735x over previous
//
#include <hip/hip_runtime.h>
#include <cstddef>

// Problem constants (MultiHeadKvtAttention): B=8, N=1024, DIM=768, H=12, D=64, TOPK=100
#define DIMC 768
#define HEADS 12
#define HEAD_DIM 64
#define TOPK 100
#define SCALE 0.125f
#define BATCH 8
#define SEQ 1024
#define RB 8       // rows per attention block (one 64-lane wave per row)
#define CAP 128    // compacted-index capacity per row (fallback loop if exceeded)
#define ATHR 512   // 8 waves

typedef _Float16 f16;
typedef __attribute__((ext_vector_type(8))) _Float16 f16x8;
typedef __attribute__((ext_vector_type(8))) __bf16 bf16x8;
typedef __attribute__((ext_vector_type(4))) float f32x4;
typedef unsigned short u16;

// Row layout of the qkv workspace (u16 units, stride 4608 = 2304 f32):
//   [0,1536)    : Q fp32 (768 floats)
//   [1536,2304) : Kh fp16 (768)   -- written by GEMM1 epilogue (split)
//   [2304,3072) : Kl fp16 (768)   -- residual
//   [3072,4608) : V fp32 (768 floats)

__device__ __forceinline__ unsigned mkey(float f) {
  // monotonic float->uint transform: a > b  <=>  mkey(a) > mkey(b)
  unsigned u = __float_as_uint(f);
  return u ^ ((unsigned)((int)u >> 31) | 0x80000000u);
}

// Exact 2-way bf16 split for the GEMM operands (error ~2^-17 rel, proven r5).
__device__ __forceinline__ void split_pack4(float4 f, uint2& ph, uint2& pl) {
  unsigned u0 = __float_as_uint(f.x), u1 = __float_as_uint(f.y);
  unsigned u2 = __float_as_uint(f.z), u3 = __float_as_uint(f.w);
  float r0 = f.x - __uint_as_float(u0 & 0xFFFF0000u);
  float r1 = f.y - __uint_as_float(u1 & 0xFFFF0000u);
  float r2 = f.z - __uint_as_float(u2 & 0xFFFF0000u);
  float r3 = f.w - __uint_as_float(u3 & 0xFFFF0000u);
  ph.x = (u0 >> 16) | (u1 & 0xFFFF0000u);
  ph.y = (u2 >> 16) | (u3 & 0xFFFF0000u);
  pl.x = (__float_as_uint(r0) >> 16) | (__float_as_uint(r1) & 0xFFFF0000u);
  pl.y = (__float_as_uint(r2) >> 16) | (__float_as_uint(r3) & 0xFFFF0000u);
}

// ---------------------------------------------------------------------------
// Split-bf16 MFMA GEMM (3-term, fp32-accurate). KSPLIT: tiles whose columns
// fall in [768,1536) (the K third of qkv) are written as fp16 hi/lo pairs
// in-place (same bytes as the fp32 K would occupy) instead of fp32.
// ---------------------------------------------------------------------------
template <int A_SPLIT, bool BIAS, bool KSPLIT>
__global__ __launch_bounds__(256) void gemm_mfma_split(
    const float* __restrict__ Af,
    const u16* __restrict__ Ah_g, const u16* __restrict__ Al_g,
    const float* __restrict__ W,
    const float* __restrict__ bias, float* __restrict__ C,
    int M, int K, int N) {
  __shared__ u16 Ah[128][32], Al[128][32];  // [m][k]
  __shared__ u16 Bh[128][32], Bl[128][32];  // [n][k] (transposed W)

  const int t = threadIdx.x;
  const int w = t >> 6, l = t & 63;
  const int wr = w >> 1, wc = w & 1;
  const int row0 = blockIdx.y * 128, col0 = blockIdx.x * 128;
  const int fr = l & 15, fq = l >> 4;

  f32x4 acc[4][4];
#pragma unroll
  for (int i = 0; i < 4; ++i)
#pragma unroll
    for (int j = 0; j < 4; ++j) acc[i][j] = (f32x4){0.f, 0.f, 0.f, 0.f};

  const int a_row = t >> 1;
  const int a_k0 = (t & 1) * 16;
  const int w_col = t & 127;
  const int w_kh = (t >> 7) * 16;

  for (int k0 = 0; k0 < K; k0 += 32) {
    if constexpr (A_SPLIT == 0) {
      const float* ap = Af + (size_t)(row0 + a_row) * K + k0 + a_k0;
#pragma unroll
      for (int q = 0; q < 4; ++q) {
        float4 v = *(const float4*)(ap + q * 4);
        uint2 ph, pl;
        split_pack4(v, ph, pl);
        *(uint2*)&Ah[a_row][a_k0 + q * 4] = ph;
        *(uint2*)&Al[a_row][a_k0 + q * 4] = pl;
      }
    } else {
      const size_t off = (size_t)(row0 + a_row) * K + k0 + a_k0;
      *(uint4*)&Ah[a_row][a_k0] = *(const uint4*)(Ah_g + off);
      *(uint4*)&Ah[a_row][a_k0 + 8] = *(const uint4*)(Ah_g + off + 8);
      *(uint4*)&Al[a_row][a_k0] = *(const uint4*)(Al_g + off);
      *(uint4*)&Al[a_row][a_k0 + 8] = *(const uint4*)(Al_g + off + 8);
    }
    {
      const float* wp = W + (size_t)(k0 + w_kh) * N + col0 + w_col;
      float wv[16];
#pragma unroll
      for (int j = 0; j < 16; ++j) wv[j] = wp[(size_t)j * N];
#pragma unroll
      for (int g = 0; g < 4; ++g) {
        float4 v = make_float4(wv[g * 4], wv[g * 4 + 1], wv[g * 4 + 2], wv[g * 4 + 3]);
        uint2 ph, pl;
        split_pack4(v, ph, pl);
        *(uint2*)&Bh[w_col][w_kh + g * 4] = ph;
        *(uint2*)&Bl[w_col][w_kh + g * 4] = pl;
      }
    }
    __syncthreads();

    bf16x8 fah[4], fal[4], fbh[4], fbl[4];
#pragma unroll
    for (int mf = 0; mf < 4; ++mf) {
      fah[mf] = *(const bf16x8*)&Ah[wr * 64 + mf * 16 + fr][fq * 8];
      fal[mf] = *(const bf16x8*)&Al[wr * 64 + mf * 16 + fr][fq * 8];
    }
#pragma unroll
    for (int nf = 0; nf < 4; ++nf) {
      fbh[nf] = *(const bf16x8*)&Bh[wc * 64 + nf * 16 + fr][fq * 8];
      fbl[nf] = *(const bf16x8*)&Bl[wc * 64 + nf * 16 + fr][fq * 8];
    }
#pragma unroll
    for (int mf = 0; mf < 4; ++mf)
#pragma unroll
      for (int nf = 0; nf < 4; ++nf) {
        acc[mf][nf] = __builtin_amdgcn_mfma_f32_16x16x32_bf16(fah[mf], fbh[nf], acc[mf][nf], 0, 0, 0);
        acc[mf][nf] = __builtin_amdgcn_mfma_f32_16x16x32_bf16(fah[mf], fbl[nf], acc[mf][nf], 0, 0, 0);
        acc[mf][nf] = __builtin_amdgcn_mfma_f32_16x16x32_bf16(fal[mf], fbh[nf], acc[mf][nf], 0, 0, 0);
      }
    __syncthreads();
  }

  // ---- epilogue ----
  const bool kzone = KSPLIT && (col0 >= 768) && (col0 < 1536);
#pragma unroll
  for (int mf = 0; mf < 4; ++mf) {
    const int r0 = row0 + wr * 64 + mf * 16 + fq * 4;
#pragma unroll
    for (int nf = 0; nf < 4; ++nf) {
      const int c = col0 + wc * 64 + nf * 16 + fr;
      if (kzone) {
        // write fp16 hi/lo split in-place: kh at u16[1536+(c-768)] = [c+768],
        // kl at u16[2304+(c-768)] = [c+1536] within the 4608-u16 row
        f16* cb = (f16*)C;
#pragma unroll
        for (int r = 0; r < 4; ++r) {
          float v = acc[mf][nf][r];
          f16 hh = (f16)v;
          f16 hl = (f16)(v - (float)hh);
          f16* rp = cb + (size_t)(r0 + r) * 4608;
          rp[c + 768] = hh;
          rp[c + 1536] = hl;
        }
      } else {
        float bb = 0.f;
        if (BIAS) bb = bias[c];
#pragma unroll
        for (int r = 0; r < 4; ++r)
          C[(size_t)(r0 + r) * N + c] = acc[mf][nf][r] + bb;
      }
    }
  }
}

// ---------------------------------------------------------------------------
// Fused attention, exact top-k. Scores computed on the MFMA pipe:
// Q split to fp16 hi/lo in LDS once; each wave loads K fp16-pair fragments
// DIRECTLY from global (no LDS staging, no extra barriers) and runs 3-term
// f16 MFMAs (error ~2^-22 — fp32-grade, selection flips at round-5 level).
// Selection: bisection with ballot+popcll counting (scalar pipe).
// PV: readfirstlane scalar-base gathers. LDS 42 KB -> 3 blocks/CU.
// ---------------------------------------------------------------------------
__global__ __launch_bounds__(ATHR) void attn_topk(
    const float* __restrict__ qkv,
    u16* __restrict__ aout_h, u16* __restrict__ aout_l) {
  __shared__ float s[RB][SEQ];                     // 32 KB scores
  __shared__ __align__(16) f16 Qh[16][64];         // 2 KB (rows 8-15 unused)
  __shared__ __align__(16) f16 Ql[16][64];         // 2 KB
  __shared__ unsigned short idxl[RB][CAP];         // 2 KB
  __shared__ float pl[RB][CAP];                    // 4 KB

  const int t = threadIdx.x;
  const int n0 = blockIdx.x * RB;
  const int bh = blockIdx.y;
  const int b = bh / HEADS, h = bh - b * HEADS;
  const float* qf = qkv + (size_t)b * SEQ * (3 * DIMC);      // b's f32 rows
  const f16* kb = (const f16*)qkv + (size_t)b * SEQ * 4608 + 1536 + h * 64;
  // row n: kh = kb + n*4608 (+768 for kl)

  // ---- Q load + scale + fp16 split (one element per thread) ----
  {
    const int r = t >> 6, d = t & 63;
    float q = qf[(size_t)(n0 + r) * (3 * DIMC) + h * 64 + d] * SCALE;
    f16 hh = (f16)q;
    Qh[r][d] = hh;
    Ql[r][d] = (f16)(q - (float)hh);
    // rows 8..15 stay garbage: their MFMA output rows are discarded
  }
  __syncthreads();

  const int w = t >> 6, l = t & 63;
  const int fr = l & 15, fq = l >> 4;

  // ---- scores via MFMA: wave w owns col-tiles [w*8, w*8+8) ----
  {
    // A fragments (row=fr, k=fq*8+reg; second k-step at +32) — loaded once
    f16x8 ah0 = *(const f16x8*)&Qh[fr][fq * 8];
    f16x8 ah1 = *(const f16x8*)&Qh[fr][32 + fq * 8];
    f16x8 al0 = *(const f16x8*)&Ql[fr][fq * 8];
    f16x8 al1 = *(const f16x8*)&Ql[fr][32 + fq * 8];
#pragma unroll
    for (int i = 0; i < 8; ++i) {
      const int tile = w * 8 + i;
      const f16* kr = kb + (size_t)(tile * 16 + fr) * 4608;
      f16x8 bh0 = *(const f16x8*)(kr + fq * 8);
      f16x8 bh1 = *(const f16x8*)(kr + 32 + fq * 8);
      f16x8 bl0 = *(const f16x8*)(kr + 768 + fq * 8);
      f16x8 bl1 = *(const f16x8*)(kr + 768 + 32 + fq * 8);
      f32x4 acc = (f32x4){0.f, 0.f, 0.f, 0.f};
      acc = __builtin_amdgcn_mfma_f32_16x16x32_f16(ah0, bh0, acc, 0, 0, 0);
      acc = __builtin_amdgcn_mfma_f32_16x16x32_f16(ah0, bl0, acc, 0, 0, 0);
      acc = __builtin_amdgcn_mfma_f32_16x16x32_f16(al0, bh0, acc, 0, 0, 0);
      acc = __builtin_amdgcn_mfma_f32_16x16x32_f16(ah1, bh1, acc, 0, 0, 0);
      acc = __builtin_amdgcn_mfma_f32_16x16x32_f16(ah1, bl1, acc, 0, 0, 0);
      acc = __builtin_amdgcn_mfma_f32_16x16x32_f16(al1, bh1, acc, 0, 0, 0);
      if (fq < 2) {  // C/D row = fq*4+r (keep rows 0-7), col = tile*16+fr
#pragma unroll
        for (int r = 0; r < 4; ++r) s[fq * 4 + r][tile * 16 + fr] = acc[r];
      }
    }
  }
  __syncthreads();
  // ======== everything below is wave-local (wave w owns row w) ========

  const int row = w;

  // ---- pull row scores into registers: lane l owns cols l + 64j ----
  float sc[16];
  unsigned ky[16];
#pragma unroll
  for (int j = 0; j < 16; ++j) sc[j] = s[row][l + 64 * j];
#pragma unroll
  for (int j = 0; j < 16; ++j) ky[j] = mkey(sc[j]);

  // ---- exact k-th largest key via bisection; ballot+popcll counting ----
  unsigned cur = 0u;
  for (int bit = 31; bit >= 0; --bit) {
    const unsigned T = cur | (1u << bit);
    int c = 0;
#pragma unroll
    for (int j = 0; j < 16; ++j)
      c += (int)__popcll(__ballot(ky[j] >= T));
    if (c >= TOPK) {  // c is scalar-uniform -> no divergence
      cur = T;
      if (c == TOPK) break;
    }
  }

  // ---- row max ----
  float mx = sc[0];
#pragma unroll
  for (int j = 1; j < 16; ++j) mx = fmaxf(mx, sc[j]);
#pragma unroll
  for (int off = 32; off > 0; off >>= 1) mx = fmaxf(mx, __shfl_xor(mx, off, 64));

  // ---- masked exp + sum + ballot compaction (single pass) ----
  float sum = 0.f;
  unsigned cbase = 0;
#pragma unroll
  for (int j = 0; j < 16; ++j) {
    const bool keep = ky[j] >= cur;  // matches reference `attn >= kth`
    const float e = keep ? __expf(sc[j] - mx) : 0.f;
    sum += e;
    const unsigned long long mask = __ballot(keep);
    if (keep) {
      const unsigned pos = cbase + (unsigned)__popcll(mask & ((1ull << l) - 1ull));
      if (pos < CAP) {
        idxl[row][pos] = (unsigned short)(l + 64 * j);
        pl[row][pos] = e;
      }
    }
    cbase += (unsigned)__popcll(mask);
  }
  const unsigned cnt = cbase;  // uniform
#pragma unroll
  for (int off = 32; off > 0; off >>= 1) sum += __shfl_xor(sum, off, 64);
  const float rinv = 1.f / sum;

  // ---- PV: sparse gather, scalar row bases via readfirstlane ----
  {
    const float* vb = qf + 1536 + h * 64;  // V f32 base (row stride 2304 f32)
    float o = 0.f;
    if (cnt <= CAP) {
      unsigned j = 0;
      for (; j + 8 <= cnt; j += 8) {
        float pv[8], vv[8];
#pragma unroll
        for (int q = 0; q < 8; ++q) {
          const int m = __builtin_amdgcn_readfirstlane((int)idxl[row][j + q]);
          vv[q] = vb[(size_t)m * (3 * DIMC) + l];
          pv[q] = pl[row][j + q];
        }
#pragma unroll
        for (int q = 0; q < 8; ++q) o = fmaf(pv[q], vv[q], o);
      }
      for (; j < cnt; ++j) {
        const int m = __builtin_amdgcn_readfirstlane((int)idxl[row][j]);
        o = fmaf(pl[row][j], vb[(size_t)m * (3 * DIMC) + l], o);
      }
    } else {  // tie-overflow fallback (cnt > CAP: vanishingly rare)
      for (int m = 0; m < SEQ; ++m) {
        float v = s[row][m];
        if (mkey(v) >= cur) o = fmaf(__expf(v - mx), vb[(size_t)m * (3 * DIMC) + l], o);
      }
    }
    // write output as exact hi/lo bf16 split (consumed by MFMA proj GEMM)
    const float r = o * rinv;
    const unsigned u = __float_as_uint(r);
    const float rl = r - __uint_as_float(u & 0xFFFF0000u);
    const size_t idx = ((size_t)b * SEQ + n0 + row) * DIMC + h * 64 + l;
    aout_h[idx] = (u16)(u >> 16);
    aout_l[idx] = (u16)(__float_as_uint(rl) >> 16);
  }
}

// ---------------------------------------------------------------------------
extern "C" void kernel_launch(void* const* d_in, const int* in_sizes, int n_in,
                              void* d_out, int out_size, void* d_ws, size_t ws_size,
                              hipStream_t stream) {
  (void)in_sizes; (void)n_in; (void)out_size; (void)ws_size;
  const float* x      = (const float*)d_in[0];  // [8,1024,768]
  const float* w_qkv  = (const float*)d_in[1];  // [768,2304]
  const float* w_proj = (const float*)d_in[2];  // [768,768]
  const float* b_proj = (const float*)d_in[3];  // [768]
  float* out = (float*)d_out;                   // [8,1024,768]

  const int M = BATCH * SEQ;                    // 8192
  float* qkv = (float*)d_ws;                    // [8192, 2304] (75.5 MB; K third holds fp16 splits)
  u16* ah2 = (u16*)(qkv + (size_t)M * (3 * DIMC));  // [8192,768] bf16-hi (12.6 MB)
  u16* al2 = ah2 + (size_t)M * DIMC;                // [8192,768] bf16-lo (12.6 MB)
  // total ws = 100.66 MB (unchanged from proven layout)

  // 1) QKV projection (split-bf16 MFMA; K tiles written as fp16 hi/lo in-place)
  dim3 g1((3 * DIMC) / 128, M / 128);
  gemm_mfma_split<0, false, true><<<g1, dim3(256), 0, stream>>>(
      x, nullptr, nullptr, w_qkv, nullptr, qkv, M, DIMC, 3 * DIMC);
  // 2) fused top-k attention (MFMA scores; outputs hi/lo bf16 split)
  dim3 g2(SEQ / RB, BATCH * HEADS);
  attn_topk<<<g2, dim3(ATHR), 0, stream>>>(qkv, ah2, al2);
  // 3) output projection + bias (A pre-split by attn)
  dim3 g3(DIMC / 128, M / 128);
  gemm_mfma_split<1, true, false><<<g3, dim3(256), 0, stream>>>(
      nullptr, ah2, al2, w_proj, b_proj, out, M, DIMC, DIMC);
}